// Round 5
// baseline (308.309 us; speedup 1.0000x reference)
//
#include <hip/hip_runtime.h>
#include <stdint.h>

#define B_  4
#define T_  2048
#define C_  1024
#define H_  16
#define HS_ 64
#define M_  (B_*T_)   // 8192
#define K_  C_        // 1024

typedef unsigned short u16;
typedef float v4f __attribute__((ext_vector_type(4)));
typedef short v8s __attribute__((ext_vector_type(8)));
typedef u16   v4u __attribute__((ext_vector_type(4)));
typedef unsigned int u32;
typedef u32 v2u32 __attribute__((ext_vector_type(2)));

__device__ __forceinline__ u16 f2bf(float f){
  unsigned u = __float_as_uint(f);
  u += 0x7fffu + ((u >> 16) & 1u);          // round-to-nearest-even
  return (u16)(u >> 16);
}

// pack two f32 -> one u32 of 2x bf16 (lo = a, hi = b), single HW instruction
__device__ __forceinline__ u32 cvt_pk_bf16(float a, float b){
  u32 r;
  asm("v_cvt_pk_bf16_f32 %0, %1, %2" : "=v"(r) : "v"(a), "v"(b));
  return r;
}

__device__ __forceinline__ void async16(const void* g, void* l){
  __builtin_amdgcn_global_load_lds(
      (const __attribute__((address_space(1))) unsigned int*)g,
      (__attribute__((address_space(3))) unsigned int*)l,
      16, 0, 0);
}

// ---------------- f32 -> bf16 conversion (4 elems/thread)
__global__ void conv_f32_bf16(const float* __restrict__ src, u16* __restrict__ dst){
  int i = (blockIdx.x * 256 + threadIdx.x) * 4;
  v4f v = *(const v4f*)(src + i);
  v4u o;
  #pragma unroll
  for (int j = 0; j < 4; j++) o[j] = f2bf(v[j]);
  *(v4u*)(dst + i) = o;
}

// ---------------- weight transpose: 3x (H,C,HS) f32 -> bf16 WallT[n][c], n = tensor*1024 + h*64 + d
__global__ void transpose_w(const float* __restrict__ Wq, const float* __restrict__ Wk,
                            const float* __restrict__ Wv, u16* __restrict__ wallT){
  int idx = blockIdx.x * 256 + threadIdx.x;      // 3072*1024 threads
  int n = idx >> 10, c = idx & 1023;
  int tensor = n >> 10;
  int h = (n >> 6) & 15;
  int d = n & 63;
  const float* W = (tensor == 0) ? Wq : ((tensor == 1) ? Wk : Wv);
  wallT[idx] = f2bf(W[((size_t)(h * C_ + c)) * HS_ + d]);
}

// Q pre-scale: scores use exp2(q.k * 0.125 * log2(e)) -> fold into Q once.
#define QSCALE 0.1803368801111204f

// ---------------- GEMM  out(M x N) = A(M x K) * Bt(N x K)^T  (A, Bt bf16; fp32 acc)
// v3: fragment-ordered LDS. r4 counters: 6.29M bank conflicts/dispatch -- row-major
// [128][32] tiles give frag reads an 8-way bank collision (64B row stride => bank
// start (16*l15+4*quad)%32, only 8 distinct groups). Since global_load_lds takes a
// per-lane GLOBAL source with a linear LDS dest, stage granules in FRAGMENT order:
// slot(m-tile, k-granule, row). Each frag read is then a contiguous 1KB wave read
// (addr = lane*16B) = conflict-free. Zero extra ALU; same data; epilogue unchanged.
// Keeps the 2-phase dbuf (one barrier per K-step) from v2.
template<int MODE>
__global__ __launch_bounds__(256)
void gemm_bt(const u16* __restrict__ A, const u16* __restrict__ Bt,
             const float* __restrict__ bias,
             u16* __restrict__ o0, u16* __restrict__ o1, u16* __restrict__ o2,
             float* __restrict__ o0f)
{
  __shared__ __align__(16) u16 sA[2][128 * 32];
  __shared__ __align__(16) u16 sB[2][128 * 32];
  const int tid  = threadIdx.x;
  const int lane = tid & 63;
  const int wave = tid >> 6;
  const int l15  = lane & 15, quad = lane >> 4;
  const int wm   = wave >> 1, wn = wave & 1;
  const int m0   = blockIdx.y * 128;
  const int n0   = blockIdx.x * 128;

  v4f acc[4][4] = {};

  // staging slots: slot s holds granule (tile = s>>6, kgran = (s>>4)&3, row = s&15)
  // LDS dest stays linear (s*16B -> wave-uniform base + lane*16); global source is
  // pre-permuted so frag reads come out contiguous.
  const int s0 = tid, s1 = tid + 256;
  const int ar0 = ((s0 >> 6) << 4) + (s0 & 15);   // tile*16 + row
  const int ac0 = ((s0 >> 4) & 3) << 4;           // k-granule byte offset (0,16,32,48)
  const int ar1 = ((s1 >> 6) << 4) + (s1 & 15);
  const int ac1 = ((s1 >> 4) & 3) << 4;

  const char* Ab = (const char*)A;
  const char* Bb = (const char*)Bt;

  // prologue: stage K-tile 0 into buffer 0
  async16(Ab + ((size_t)(m0 + ar0) * K_) * 2 + ac0, (char*)sA[0] + s0 * 16);
  async16(Ab + ((size_t)(m0 + ar1) * K_) * 2 + ac1, (char*)sA[0] + s1 * 16);
  async16(Bb + ((size_t)(n0 + ar0) * K_) * 2 + ac0, (char*)sB[0] + s0 * 16);
  async16(Bb + ((size_t)(n0 + ar1) * K_) * 2 + ac1, (char*)sB[0] + s1 * 16);
  __syncthreads();

  int cur = 0;
  for (int kk = 0; kk < K_; kk += 32){
    const int nxt = cur ^ 1;
    if (kk + 32 < K_){
      const int k2b = (kk + 32) * 2;
      async16(Ab + ((size_t)(m0 + ar0) * K_) * 2 + k2b + ac0, (char*)sA[nxt] + s0 * 16);
      async16(Ab + ((size_t)(m0 + ar1) * K_) * 2 + k2b + ac1, (char*)sA[nxt] + s1 * 16);
      async16(Bb + ((size_t)(n0 + ar0) * K_) * 2 + k2b + ac0, (char*)sB[nxt] + s0 * 16);
      async16(Bb + ((size_t)(n0 + ar1) * K_) * 2 + k2b + ac1, (char*)sB[nxt] + s1 * 16);
    }

    // fragment reads: tile t block = 512 elems; lane reads elems [lane*8 .. lane*8+7]
    v8s af[4], bfr[4];
    const u16* pa = sA[cur] + (size_t)(wm * 4) * 512 + lane * 8;
    const u16* pb = sB[cur] + (size_t)(wn * 4) * 512 + lane * 8;
    #pragma unroll
    for (int mi = 0; mi < 4; mi++) af[mi]  = *(const v8s*)(pa + mi * 512);
    #pragma unroll
    for (int ni = 0; ni < 4; ni++) bfr[ni] = *(const v8s*)(pb + ni * 512);

    #pragma unroll
    for (int mi = 0; mi < 4; mi++)
      #pragma unroll
      for (int ni = 0; ni < 4; ni++)
        acc[mi][ni] = __builtin_amdgcn_mfma_f32_16x16x32_bf16(af[mi], bfr[ni], acc[mi][ni], 0, 0, 0);

    __syncthreads();   // drains prefetch vmcnt + guards buffer swap (one barrier/K-step)
    cur = nxt;
  }

  if constexpr (MODE == 0){
    #pragma unroll
    for (int ni = 0; ni < 4; ni++){
      const int ng = n0 + wn * 64 + ni * 16 + l15;
      const int tensor = ng >> 10;
      const int hh = (ng >> 6) & 15;
      const int d  = ng & 63;
      #pragma unroll
      for (int mi = 0; mi < 4; mi++){
        const int mbase = m0 + wm * 64 + mi * 16 + quad * 4;
        const int bb = mbase >> 11;
        const int tt = mbase & 2047;
        if (tensor == 2){
          v4u pk;
          #pragma unroll
          for (int r = 0; r < 4; r++) pk[r] = f2bf(acc[mi][ni][r]);
          *(v4u*)(o2 + ((size_t)((bb * H_ + hh) * HS_ + d)) * T_ + tt) = pk;   // vT: contiguous in t
        } else if (tensor == 0){
          #pragma unroll
          for (int r = 0; r < 4; r++)
            o0[((size_t)((bb * H_ + hh)) * T_ + tt + r) * HS_ + d] = f2bf(acc[mi][ni][r] * QSCALE);
        } else {
          #pragma unroll
          for (int r = 0; r < 4; r++)
            o1[((size_t)((bb * H_ + hh)) * T_ + tt + r) * HS_ + d] = f2bf(acc[mi][ni][r]);
        }
      }
    }
  } else {
    #pragma unroll
    for (int ni = 0; ni < 4; ni++){
      const int ng = n0 + wn * 64 + ni * 16 + l15;
      const float bv = bias[ng];
      #pragma unroll
      for (int mi = 0; mi < 4; mi++){
        const int mbase = m0 + wm * 64 + mi * 16 + quad * 4;
        #pragma unroll
        for (int r = 0; r < 4; r++)
          o0f[(size_t)(mbase + r) * C_ + ng] = acc[mi][ni][r] + bv;   // f32 output
      }
    }
  }
}

// ---------------- flash attention v8 = v6 + P-stride fix + setprio.
// v6's residual 4.3M bank conflicts are the P round-trip: row stride 80 elems
// (160B = 8 banks * l15) -> 4-way collisions on b64 writes and b128 reads.
// Stride 88 (176B: 16B-aligned, 44 banks ≡ 12*l15 mod 32) spreads to <=2-way.
// LDS 36 -> 38.9 KB, still 4 blocks/CU. s_setprio(1) around MFMA clusters (T5's
// measured +4-7% regime: independent blocks at different phases).
__global__ __launch_bounds__(512, 4)
void attn(const u16* __restrict__ Q, const u16* __restrict__ Kb_, const u16* __restrict__ Vt,
          u16* __restrict__ O)
{
  __shared__ __align__(16) u16 sK[64 * 64];       // [t][d-swizzled]  8 KB
  __shared__ __align__(16) u16 sV[64 * 64];       // [d][t-swizzled]  8 KB
  __shared__ __align__(16) u16 Plds[8][16][88];   // per-wave P tile [q][k], 176B row stride
  const int tid  = threadIdx.x;                   // 0..511
  const int lane = tid & 63;
  const int wave = tid >> 6;                      // 0..7
  const int l15  = lane & 15, quad = lane >> 4;
  const int pp   = blockIdx.y & 7;                // pair index 0..7 over 16 q-tiles of 128
  const int bh   = blockIdx.x * 8 + (blockIdx.y >> 3);  // XCD-grouped b*H+h

  const u16* Qb = Q   + (size_t)bh * T_ * HS_;
  const u16* Kb = Kb_ + (size_t)bh * T_ * HS_;
  const u16* Vb = Vt  + (size_t)bh * HS_ * T_;    // vT: [d][t]
  const int b = bh >> 4, h = bh & 15;

  // staging geometry: granule g (16 B); 512 threads stage one K granule + one V granule.
  // K granule (t, c): LDS slot t*8 + (c ^ (t&7)); source K[k0+t][c*8..]
  // V granule (d, c): LDS slot d*8 + (c ^ (d&7)); source vT[d][k0 + c*8..]
  const int g  = tid;
  const int tg = g >> 3;                          // row 0..63
  const int sw = ((g & 7) ^ (tg & 7)) << 4;
  const char* Kby = (const char*)Kb;
  const char* Vby = (const char*)Vb;
  const int koff = tg * 128 + sw;
  const int voff = tg * (T_ * 2) + sw;
  char* sKp = (char*)sK + g * 16;
  char* sVp = (char*)sV + g * 16;

  // swizzled frag offsets (elements) within an sK/sV row
  const int fsw0 = (quad ^ (l15 & 7)) * 8;        // granule d8=quad   (k = quad*8+j)
  const int fsw1 = ((quad + 4) ^ (l15 & 7)) * 8;  // granule d8=quad+4 (k = 32+quad*8+j)

  #pragma unroll 1
  for (int ph = 0; ph < 2; ph++){
    const int qt = ph ? (15 - pp) : pp;           // q-tile (128 rows) 0..15
    const int q0 = qt * 128 + wave * 16;          // this wave's 16 q-rows

    // Q fragments (m/n=l15, k=quad*8+j), pre-scaled by QSCALE at projection
    const v8s qf0 = *(const v8s*)(Qb + (size_t)(q0 + l15) * HS_ + quad * 8);
    const v8s qf1 = *(const v8s*)(Qb + (size_t)(q0 + l15) * HS_ + 32 + quad * 8);

    v4f Oa[4] = {};
    float lsum = 0.f;                             // partial sum for q-row q0+l15

    const int ktmax = 2 * qt + 1;                 // kv-tiles (64 keys) covering q-tile
    for (int kt = 0; kt <= ktmax; kt++){
      const int k0 = kt * 64;
      // ---- stage K,V tiles (once per block)
      async16(Kby + (size_t)k0 * 128 + koff, sKp);
      async16(Vby + (size_t)k0 * 2   + voff, sVp);
      __syncthreads();

      // waves whose rows are entirely left of this kv-tile contribute nothing
      if (k0 <= q0 + 15){
        // ---- S^T = K Q^T : C/D col(l15)=q-row, row(quad*4+reg)=k-pos
        v4f sacc[4] = {};
        __builtin_amdgcn_s_setprio(1);
        #pragma unroll
        for (int nt = 0; nt < 4; nt++){
          const u16* kr = sK + (nt * 16 + l15) * 64;
          v8s kf0 = *(const v8s*)(kr + fsw0);
          v8s kf1 = *(const v8s*)(kr + fsw1);
          sacc[nt] = __builtin_amdgcn_mfma_f32_16x16x32_bf16(kf0, qf0, sacc[nt], 0, 0, 0);
          sacc[nt] = __builtin_amdgcn_mfma_f32_16x16x32_bf16(kf1, qf1, sacc[nt], 0, 0, 0);
        }
        __builtin_amdgcn_s_setprio(0);
        const bool diag = (k0 + 63 > q0);         // masking possible in this tile
        const int qrow_rel = (q0 - k0) + l15;     // mask when nt*16+quad*4+r > qrow_rel

        // ---- p = 2^s, causal mask (diag tiles only), scalar row-sum, packed P write
        #pragma unroll
        for (int nt = 0; nt < 4; nt++){
          float p0 = exp2f(sacc[nt][0]);
          float p1 = exp2f(sacc[nt][1]);
          float p2 = exp2f(sacc[nt][2]);
          float p3 = exp2f(sacc[nt][3]);
          if (diag){
            const int kbase = nt * 16 + quad * 4;
            if (kbase + 0 > qrow_rel) p0 = 0.f;
            if (kbase + 1 > qrow_rel) p1 = 0.f;
            if (kbase + 2 > qrow_rel) p2 = 0.f;
            if (kbase + 3 > qrow_rel) p3 = 0.f;
          }
          lsum += (p0 + p1) + (p2 + p3);
          v2u32 w;
          w[0] = cvt_pk_bf16(p0, p1);
          w[1] = cvt_pk_bf16(p2, p3);
          *(v2u32*)&Plds[wave][l15][nt * 16 + quad * 4] = w;   // one b64 store
        }

        // ---- P: [q][k] -> A fragments via per-wave LDS round-trip (same-wave, in-order DS)
        asm volatile("" ::: "memory");
        const v8s pf0 = *(const v8s*)&Plds[wave][l15][quad * 8];
        const v8s pf1 = *(const v8s*)&Plds[wave][l15][32 + quad * 8];
        __builtin_amdgcn_s_setprio(1);
        #pragma unroll
        for (int nt = 0; nt < 4; nt++){
          const u16* vr = sV + (nt * 16 + l15) * 64;
          v8s vf0 = *(const v8s*)(vr + fsw0);
          v8s vf1 = *(const v8s*)(vr + fsw1);
          Oa[nt] = __builtin_amdgcn_mfma_f32_16x16x32_bf16(pf0, vf0, Oa[nt], 0, 0, 0);
          Oa[nt] = __builtin_amdgcn_mfma_f32_16x16x32_bf16(pf1, vf1, Oa[nt], 0, 0, 0);
        }
        __builtin_amdgcn_s_setprio(0);
      }
      __syncthreads();   // everyone done reading sK/sV before next stage overwrites
    }

    // row-sum finalize: quads hold disjoint k-ranges of row q0+l15 -> combine, redistribute
    float rs = lsum;
    rs += __shfl_xor(rs, 16);
    rs += __shfl_xor(rs, 32);                     // every lane: full sum for row q0+l15
    #pragma unroll
    for (int reg = 0; reg < 4; reg++){
      const float rsq = __shfl(rs, quad * 4 + reg);   // sum for row q0+quad*4+reg
      const float inv = (rsq > 0.f) ? (1.f / rsq) : 0.f;
      const int t = q0 + quad * 4 + reg;
      #pragma unroll
      for (int nt = 0; nt < 4; nt++)
        O[((size_t)(b * T_ + t)) * C_ + h * HS_ + nt * 16 + l15] = f2bf(Oa[nt][reg] * inv);
    }
  }
}

extern "C" void kernel_launch(void* const* d_in, const int* in_sizes, int n_in,
                              void* d_out, int out_size, void* d_ws, size_t ws_size,
                              hipStream_t stream)
{
  const float* x     = (const float*)d_in[0];
  const float* Wq    = (const float*)d_in[1];
  const float* Wk    = (const float*)d_in[2];
  const float* Wv    = (const float*)d_in[3];
  const float* Wproj = (const float*)d_in[4];
  const float* bproj = (const float*)d_in[5];
  float* out = (float*)d_out;   // f32 output

  u16* xhat   = (u16*)d_ws;                       // (B*T, C)    dead after gemm<0>
  u16* att    = xhat;                             // (B*T, C)    written by attn
  u16* q_ws   = xhat  + (size_t)M_ * C_;
  u16* k_ws   = q_ws  + (size_t)M_ * C_;
  u16* vt_ws  = k_ws  + (size_t)M_ * C_;
  u16* wallT  = vt_ws + (size_t)M_ * C_;          // (3072,1024)
  u16* wprojT = wallT + (size_t)3 * C_ * K_;      // (1024,1024)

  conv_f32_bf16<<<dim3((M_ * C_) / 1024), dim3(256), 0, stream>>>(x, xhat);
  transpose_w<<<dim3((3 * C_ * K_) / 256), dim3(256), 0, stream>>>(Wq, Wk, Wv, wallT);
  conv_f32_bf16<<<dim3((C_ * C_) / 1024), dim3(256), 0, stream>>>(Wproj, wprojT);
  gemm_bt<0><<<dim3(24, 64), dim3(256), 0, stream>>>(xhat, wallT, nullptr,
                                                     q_ws, k_ws, vt_ws, nullptr);
  attn<<<dim3(8, 64), dim3(512), 0, stream>>>(q_ws, k_ws, vt_ws, att);
  gemm_bt<1><<<dim3(8, 64), dim3(256), 0, stream>>>(att, wprojT, bproj,
                                                    nullptr, nullptr, nullptr, out);
}

// Round 6
// 269.991 us; speedup vs baseline: 1.1419x; 1.1419x over previous
//
#include <hip/hip_runtime.h>
#include <stdint.h>

#define B_  4
#define T_  2048
#define C_  1024
#define H_  16
#define HS_ 64
#define M_  (B_*T_)   // 8192
#define K_  C_        // 1024

typedef unsigned short u16;
typedef float v4f __attribute__((ext_vector_type(4)));
typedef short v8s __attribute__((ext_vector_type(8)));
typedef u16   v4u __attribute__((ext_vector_type(4)));
typedef unsigned int u32;
typedef u32 v2u32 __attribute__((ext_vector_type(2)));

__device__ __forceinline__ u16 f2bf(float f){
  unsigned u = __float_as_uint(f);
  u += 0x7fffu + ((u >> 16) & 1u);          // round-to-nearest-even
  return (u16)(u >> 16);
}

// pack two f32 -> one u32 of 2x bf16 (lo = a, hi = b), single HW instruction
__device__ __forceinline__ u32 cvt_pk_bf16(float a, float b){
  u32 r;
  asm("v_cvt_pk_bf16_f32 %0, %1, %2" : "=v"(r) : "v"(a), "v"(b));
  return r;
}

__device__ __forceinline__ void async16(const void* g, void* l){
  __builtin_amdgcn_global_load_lds(
      (const __attribute__((address_space(1))) unsigned int*)g,
      (__attribute__((address_space(3))) unsigned int*)l,
      16, 0, 0);
}

// ================= BLOCKED OPERAND LAYOUT =================
// bf16 matrices consumed by gemm_bt are stored granule-blocked:
//   elem(row r, col k) at  (r>>4)*K*2 + (k>>3)*128 + (r&15)*8 + (k&7)   [u16 units, K=1024]
// i.e. [r/16][K/8][16][8]. A staging wave then reads 1024 CONTIGUOUS bytes
// (coalesced) into a LINEAR LDS dest, and the MFMA fragment read
// (lane*16B) is conflict-free. r5 post-mortem: fragment-ordering the LDS via
// scattered global sources killed coalescing (111us); this keeps both.

// ---------------- f32 row-major [R][1024] -> bf16 blocked (one 8-elem granule/thread)
__global__ void conv_blocked(const float* __restrict__ src, u16* __restrict__ dst){
  int gid = blockIdx.x * 256 + threadIdx.x;
  int r  = gid >> 7;                 // row
  int kg = gid & 127;                // k-granule
  const float* s = src + ((size_t)r << 10) + (kg << 3);
  v4f a = *(const v4f*)s;
  v4f b = *(const v4f*)(s + 4);
  union { v8s v; u16 e[8]; } o;
  o.e[0]=f2bf(a[0]); o.e[1]=f2bf(a[1]); o.e[2]=f2bf(a[2]); o.e[3]=f2bf(a[3]);
  o.e[4]=f2bf(b[0]); o.e[5]=f2bf(b[1]); o.e[6]=f2bf(b[2]); o.e[7]=f2bf(b[3]);
  *(v8s*)(dst + (((size_t)(r >> 4) * 128 + kg) * 128 + ((r & 15) << 3))) = o.v;
}

// ---------------- weight transpose: 3x (H,C,HS) f32 -> bf16 blocked WallT, n = tensor*1024 + h*64 + d
__global__ void transpose_w(const float* __restrict__ Wq, const float* __restrict__ Wk,
                            const float* __restrict__ Wv, u16* __restrict__ wallT){
  int idx = blockIdx.x * 256 + threadIdx.x;      // 3072*1024 threads
  int n = idx >> 10, c = idx & 1023;
  int tensor = n >> 10;
  int h = (n >> 6) & 15;
  int d = n & 63;
  const float* W = (tensor == 0) ? Wq : ((tensor == 1) ? Wk : Wv);
  wallT[((size_t)(n >> 4) * 128 + (c >> 3)) * 128 + ((n & 15) << 3) + (c & 7)]
      = f2bf(W[((size_t)(h * C_ + c)) * HS_ + d]);
}

// Q pre-scale: scores use exp2(q.k * 0.125 * log2(e)) -> fold into Q once.
#define QSCALE 0.1803368801111204f

// ---------------- GEMM  out(M x N) = A(M x K) * Bt(N x K)^T  (A, Bt bf16 BLOCKED; fp32 acc)
// 2-phase dbuf (r4, measured 78.9us) + blocked operands: staging wave = 1024
// contiguous bytes -> linear LDS -> frag read lane*16B conflict-free (r5: 0 conflicts).
template<int MODE>
__global__ __launch_bounds__(256)
void gemm_bt(const u16* __restrict__ A, const u16* __restrict__ Bt,
             const float* __restrict__ bias,
             u16* __restrict__ o0, u16* __restrict__ o1, u16* __restrict__ o2,
             float* __restrict__ o0f)
{
  __shared__ __align__(16) u16 sA[2][128 * 32];
  __shared__ __align__(16) u16 sB[2][128 * 32];
  const int tid  = threadIdx.x;
  const int lane = tid & 63;
  const int wave = tid >> 6;
  const int l15  = lane & 15, quad = lane >> 4;
  const int wm   = wave >> 1, wn = wave & 1;
  const int m0   = blockIdx.y * 128;
  const int n0   = blockIdx.x * 128;
  const int mg0  = blockIdx.y * 8;               // row-group base
  const int ng0  = blockIdx.x * 8;

  v4f acc[4][4] = {};

  // staging slot s holds granule (tile = s>>6, kgran = (s>>4)&3, row = s&15);
  // blocked global addr for slot s at K-step kk: base(s) + kk*32 bytes.
  const int s0 = tid, s1 = tid + 256;
  const int t0 = s0 >> 6, r0 = s0 & 15, g0 = (s0 >> 4) & 3;
  const int t1 = s1 >> 6, r1 = s1 & 15, g1 = (s1 >> 4) & 3;

  const char* aS0 = (const char*)A  + ((size_t)(mg0 + t0) * 16384 + g0 * 128 + r0 * 8) * 2;
  const char* aS1 = (const char*)A  + ((size_t)(mg0 + t1) * 16384 + g1 * 128 + r1 * 8) * 2;
  const char* bS0 = (const char*)Bt + ((size_t)(ng0 + t0) * 16384 + g0 * 128 + r0 * 8) * 2;
  const char* bS1 = (const char*)Bt + ((size_t)(ng0 + t1) * 16384 + g1 * 128 + r1 * 8) * 2;

  // prologue: stage K-tile 0 into buffer 0
  async16(aS0, (char*)sA[0] + s0 * 16);
  async16(aS1, (char*)sA[0] + s1 * 16);
  async16(bS0, (char*)sB[0] + s0 * 16);
  async16(bS1, (char*)sB[0] + s1 * 16);
  __syncthreads();

  int cur = 0;
  for (int kk = 0; kk < K_; kk += 32){
    const int nxt = cur ^ 1;
    if (kk + 32 < K_){
      const size_t off = (size_t)(kk + 32) * 32;   // (kk/8+4) granule-cols * 256B
      async16(aS0 + off, (char*)sA[nxt] + s0 * 16);
      async16(aS1 + off, (char*)sA[nxt] + s1 * 16);
      async16(bS0 + off, (char*)sB[nxt] + s0 * 16);
      async16(bS1 + off, (char*)sB[nxt] + s1 * 16);
    }

    // fragment reads: tile t = 512 elems; lane reads elems [lane*8 .. lane*8+7]
    v8s af[4], bfr[4];
    const u16* pa = sA[cur] + (size_t)(wm * 4) * 512 + lane * 8;
    const u16* pb = sB[cur] + (size_t)(wn * 4) * 512 + lane * 8;
    #pragma unroll
    for (int mi = 0; mi < 4; mi++) af[mi]  = *(const v8s*)(pa + mi * 512);
    #pragma unroll
    for (int ni = 0; ni < 4; ni++) bfr[ni] = *(const v8s*)(pb + ni * 512);

    #pragma unroll
    for (int mi = 0; mi < 4; mi++)
      #pragma unroll
      for (int ni = 0; ni < 4; ni++)
        acc[mi][ni] = __builtin_amdgcn_mfma_f32_16x16x32_bf16(af[mi], bfr[ni], acc[mi][ni], 0, 0, 0);

    __syncthreads();   // drains prefetch vmcnt + guards buffer swap (one barrier/K-step)
    cur = nxt;
  }

  if constexpr (MODE == 0){
    #pragma unroll
    for (int ni = 0; ni < 4; ni++){
      const int ng = n0 + wn * 64 + ni * 16 + l15;
      const int tensor = ng >> 10;
      const int hh = (ng >> 6) & 15;
      const int d  = ng & 63;
      #pragma unroll
      for (int mi = 0; mi < 4; mi++){
        const int mbase = m0 + wm * 64 + mi * 16 + quad * 4;
        const int bb = mbase >> 11;
        const int tt = mbase & 2047;
        if (tensor == 2){
          v4u pk;
          #pragma unroll
          for (int r = 0; r < 4; r++) pk[r] = f2bf(acc[mi][ni][r]);
          *(v4u*)(o2 + ((size_t)((bb * H_ + hh) * HS_ + d)) * T_ + tt) = pk;   // vT: contiguous in t
        } else if (tensor == 0){
          #pragma unroll
          for (int r = 0; r < 4; r++)
            o0[((size_t)((bb * H_ + hh)) * T_ + tt + r) * HS_ + d] = f2bf(acc[mi][ni][r] * QSCALE);
        } else {
          #pragma unroll
          for (int r = 0; r < 4; r++)
            o1[((size_t)((bb * H_ + hh)) * T_ + tt + r) * HS_ + d] = f2bf(acc[mi][ni][r]);
        }
      }
    }
  } else {
    #pragma unroll
    for (int ni = 0; ni < 4; ni++){
      const int ng = n0 + wn * 64 + ni * 16 + l15;
      const float bv = bias[ng];
      #pragma unroll
      for (int mi = 0; mi < 4; mi++){
        const int mbase = m0 + wm * 64 + mi * 16 + quad * 4;
        #pragma unroll
        for (int r = 0; r < 4; r++)
          o0f[(size_t)(mbase + r) * C_ + ng] = acc[mi][ni][r] + bv;   // f32 output
      }
    }
  }
}

// ---------------- flash attention v8 (r5: ~7us faster than v6 per total-time delta):
// swapped QK^T, P-stride 88 (conflict-light round-trip), setprio around MFMA.
// Only change this round: O is written in the BLOCKED layout gemm<1> now expects.
__global__ __launch_bounds__(512, 4)
void attn(const u16* __restrict__ Q, const u16* __restrict__ Kb_, const u16* __restrict__ Vt,
          u16* __restrict__ O)
{
  __shared__ __align__(16) u16 sK[64 * 64];       // [t][d-swizzled]  8 KB
  __shared__ __align__(16) u16 sV[64 * 64];       // [d][t-swizzled]  8 KB
  __shared__ __align__(16) u16 Plds[8][16][88];   // per-wave P tile [q][k], 176B row stride
  const int tid  = threadIdx.x;                   // 0..511
  const int lane = tid & 63;
  const int wave = tid >> 6;                      // 0..7
  const int l15  = lane & 15, quad = lane >> 4;
  const int pp   = blockIdx.y & 7;                // pair index 0..7 over 16 q-tiles of 128
  const int bh   = blockIdx.x * 8 + (blockIdx.y >> 3);  // XCD-grouped b*H+h

  const u16* Qb = Q   + (size_t)bh * T_ * HS_;
  const u16* Kb = Kb_ + (size_t)bh * T_ * HS_;
  const u16* Vb = Vt  + (size_t)bh * HS_ * T_;    // vT: [d][t]
  const int b = bh >> 4, h = bh & 15;

  // staging geometry: granule g (16 B); 512 threads stage one K granule + one V granule.
  const int g  = tid;
  const int tg = g >> 3;                          // row 0..63
  const int sw = ((g & 7) ^ (tg & 7)) << 4;
  const char* Kby = (const char*)Kb;
  const char* Vby = (const char*)Vb;
  const int koff = tg * 128 + sw;
  const int voff = tg * (T_ * 2) + sw;
  char* sKp = (char*)sK + g * 16;
  char* sVp = (char*)sV + g * 16;

  // swizzled frag offsets (elements) within an sK/sV row
  const int fsw0 = (quad ^ (l15 & 7)) * 8;        // granule d8=quad   (k = quad*8+j)
  const int fsw1 = ((quad + 4) ^ (l15 & 7)) * 8;  // granule d8=quad+4 (k = 32+quad*8+j)

  #pragma unroll 1
  for (int ph = 0; ph < 2; ph++){
    const int qt = ph ? (15 - pp) : pp;           // q-tile (128 rows) 0..15
    const int q0 = qt * 128 + wave * 16;          // this wave's 16 q-rows

    // Q fragments (m/n=l15, k=quad*8+j), pre-scaled by QSCALE at projection
    const v8s qf0 = *(const v8s*)(Qb + (size_t)(q0 + l15) * HS_ + quad * 8);
    const v8s qf1 = *(const v8s*)(Qb + (size_t)(q0 + l15) * HS_ + 32 + quad * 8);

    v4f Oa[4] = {};
    float lsum = 0.f;                             // partial sum for q-row q0+l15

    const int ktmax = 2 * qt + 1;                 // kv-tiles (64 keys) covering q-tile
    for (int kt = 0; kt <= ktmax; kt++){
      const int k0 = kt * 64;
      // ---- stage K,V tiles (once per block)
      async16(Kby + (size_t)k0 * 128 + koff, sKp);
      async16(Vby + (size_t)k0 * 2   + voff, sVp);
      __syncthreads();

      // waves whose rows are entirely left of this kv-tile contribute nothing
      if (k0 <= q0 + 15){
        // ---- S^T = K Q^T : C/D col(l15)=q-row, row(quad*4+reg)=k-pos
        v4f sacc[4] = {};
        __builtin_amdgcn_s_setprio(1);
        #pragma unroll
        for (int nt = 0; nt < 4; nt++){
          const u16* kr = sK + (nt * 16 + l15) * 64;
          v8s kf0 = *(const v8s*)(kr + fsw0);
          v8s kf1 = *(const v8s*)(kr + fsw1);
          sacc[nt] = __builtin_amdgcn_mfma_f32_16x16x32_bf16(kf0, qf0, sacc[nt], 0, 0, 0);
          sacc[nt] = __builtin_amdgcn_mfma_f32_16x16x32_bf16(kf1, qf1, sacc[nt], 0, 0, 0);
        }
        __builtin_amdgcn_s_setprio(0);
        const bool diag = (k0 + 63 > q0);         // masking possible in this tile
        const int qrow_rel = (q0 - k0) + l15;     // mask when nt*16+quad*4+r > qrow_rel

        // ---- p = 2^s, causal mask (diag tiles only), scalar row-sum, packed P write
        #pragma unroll
        for (int nt = 0; nt < 4; nt++){
          float p0 = exp2f(sacc[nt][0]);
          float p1 = exp2f(sacc[nt][1]);
          float p2 = exp2f(sacc[nt][2]);
          float p3 = exp2f(sacc[nt][3]);
          if (diag){
            const int kbase = nt * 16 + quad * 4;
            if (kbase + 0 > qrow_rel) p0 = 0.f;
            if (kbase + 1 > qrow_rel) p1 = 0.f;
            if (kbase + 2 > qrow_rel) p2 = 0.f;
            if (kbase + 3 > qrow_rel) p3 = 0.f;
          }
          lsum += (p0 + p1) + (p2 + p3);
          v2u32 w;
          w[0] = cvt_pk_bf16(p0, p1);
          w[1] = cvt_pk_bf16(p2, p3);
          *(v2u32*)&Plds[wave][l15][nt * 16 + quad * 4] = w;   // one b64 store
        }

        // ---- P: [q][k] -> A fragments via per-wave LDS round-trip (same-wave, in-order DS)
        asm volatile("" ::: "memory");
        const v8s pf0 = *(const v8s*)&Plds[wave][l15][quad * 8];
        const v8s pf1 = *(const v8s*)&Plds[wave][l15][32 + quad * 8];
        __builtin_amdgcn_s_setprio(1);
        #pragma unroll
        for (int nt = 0; nt < 4; nt++){
          const u16* vr = sV + (nt * 16 + l15) * 64;
          v8s vf0 = *(const v8s*)(vr + fsw0);
          v8s vf1 = *(const v8s*)(vr + fsw1);
          Oa[nt] = __builtin_amdgcn_mfma_f32_16x16x32_bf16(pf0, vf0, Oa[nt], 0, 0, 0);
          Oa[nt] = __builtin_amdgcn_mfma_f32_16x16x32_bf16(pf1, vf1, Oa[nt], 0, 0, 0);
        }
        __builtin_amdgcn_s_setprio(0);
      }
      __syncthreads();   // everyone done reading sK/sV before next stage overwrites
    }

    // row-sum finalize: quads hold disjoint k-ranges of row q0+l15 -> combine, redistribute
    float rs = lsum;
    rs += __shfl_xor(rs, 16);
    rs += __shfl_xor(rs, 32);                     // every lane: full sum for row q0+l15
    const int mg = b * 128 + qt * 8 + wave;       // (b*T + t) >> 4  (t-row group)
    #pragma unroll
    for (int reg = 0; reg < 4; reg++){
      const float rsq = __shfl(rs, quad * 4 + reg);   // sum for row q0+quad*4+reg
      const float inv = (rsq > 0.f) ? (1.f / rsq) : 0.f;
      const int mrow = quad * 4 + reg;            // t & 15
      #pragma unroll
      for (int nt = 0; nt < 4; nt++){
        const int cg = h * 8 + nt * 2 + (l15 >> 3);
        O[((size_t)mg * 128 + cg) * 128 + mrow * 8 + (l15 & 7)] = f2bf(Oa[nt][reg] * inv);
      }
    }
  }
}

extern "C" void kernel_launch(void* const* d_in, const int* in_sizes, int n_in,
                              void* d_out, int out_size, void* d_ws, size_t ws_size,
                              hipStream_t stream)
{
  const float* x     = (const float*)d_in[0];
  const float* Wq    = (const float*)d_in[1];
  const float* Wk    = (const float*)d_in[2];
  const float* Wv    = (const float*)d_in[3];
  const float* Wproj = (const float*)d_in[4];
  const float* bproj = (const float*)d_in[5];
  float* out = (float*)d_out;   // f32 output

  u16* xhat   = (u16*)d_ws;                       // (B*T, C) blocked; dead after gemm<0>
  u16* att    = xhat;                             // (B*T, C) blocked; written by attn
  u16* q_ws   = xhat  + (size_t)M_ * C_;
  u16* k_ws   = q_ws  + (size_t)M_ * C_;
  u16* vt_ws  = k_ws  + (size_t)M_ * C_;
  u16* wallT  = vt_ws + (size_t)M_ * C_;          // (3072,1024) blocked
  u16* wprojT = wallT + (size_t)3 * C_ * K_;      // (1024,1024) blocked

  conv_blocked<<<dim3((M_ * C_) / 8 / 256), dim3(256), 0, stream>>>(x, xhat);
  transpose_w<<<dim3((3 * C_ * K_) / 256), dim3(256), 0, stream>>>(Wq, Wk, Wv, wallT);
  conv_blocked<<<dim3((C_ * C_) / 8 / 256), dim3(256), 0, stream>>>(Wproj, wprojT);
  gemm_bt<0><<<dim3(24, 64), dim3(256), 0, stream>>>(xhat, wallT, nullptr,
                                                     q_ws, k_ws, vt_ws, nullptr);
  attn<<<dim3(8, 64), dim3(512), 0, stream>>>(q_ws, k_ws, vt_ws, att);
  gemm_bt<1><<<dim3(8, 64), dim3(256), 0, stream>>>(att, wprojT, bproj,
                                                    nullptr, nullptr, nullptr, out);
}